// Round 4
// baseline (297.058 us; speedup 1.0000x reference)
//
#include <hip/hip_runtime.h>
#include <hip/hip_bf16.h>

// out[b,n,o] = relu( sum_m efm[b,n,m] * z[b,m,o] + bias[o] ),
// z[b,m,o]   = sum_d nfm[b,m,d] * W[o,d]        (matmul associativity)
//
// v4: 1024 blocks (2/batch, 128 out-rows each) x 256 threads (4 waves).
// z computed redundantly per block (cheap) so LDS = w_s(8K) + z_s(33.8K)
// = 42KB -> 3 blocks/CU. Phase-1 A-frags read directly from global.
// NOTE: kernel launched 3x this round (idempotent) as a timing probe:
// dur = F + K_cold + 2*K_warm; next round single-launch recovers K and F.

typedef float f32x2 __attribute__((ext_vector_type(2)));
typedef float f32x4 __attribute__((ext_vector_type(4)));
typedef short s16x8 __attribute__((ext_vector_type(8)));

#define ZSTR 264                         // padded m-stride (bf16 elems)

__device__ __forceinline__ unsigned short f2bf(float f) {
    return __builtin_bit_cast(unsigned short, __float2bfloat16(f));
}
__device__ __forceinline__ unsigned bfpair(float a, float b) {
    return (unsigned)f2bf(a) | ((unsigned)f2bf(b) << 16);
}
__device__ __forceinline__ s16x8 cvt8(f32x4 lo, f32x4 hi) {
    s16x8 r;
    #pragma unroll
    for (int j = 0; j < 4; ++j) {
        r[j]     = (short)f2bf(lo[j]);
        r[4 + j] = (short)f2bf(hi[j]);
    }
    return r;
}
// chunk-level XOR swizzle for 64-elem bf16 rows (8 chunks of 8 elems)
__device__ __forceinline__ int swz(int row, int k) {
    return row * 64 + ((((k >> 3) ^ (row & 7)) << 3) | (k & 7));
}

__global__ __launch_bounds__(256, 3)
void gconv_v4(const float* __restrict__ nfm,
              const float* __restrict__ efm,
              const float* __restrict__ W,
              const float* __restrict__ bias,
              float* __restrict__ out)
{
    __shared__ unsigned short w_s[64 * 64];      // 8 KB, swizzled, zero-padded
    __shared__ unsigned short z_s[64 * ZSTR];    // 33.8 KB, z transposed [o][m]

    const int tid   = threadIdx.x;
    const int lane  = tid & 63;
    const int wv    = tid >> 6;          // 0..3
    const int col16 = lane & 15;
    const int kg    = lane >> 4;         // 0..3
    const int kg8   = kg * 8;
    const int bid   = blockIdx.x;
    const int b     = bid >> 1;
    const int rt    = bid & 1;

    const float* nfm_b = nfm + (size_t)b * (256 * 50);
    const float* efm_b = efm + (size_t)b * (256 * 256);
    float*       out_b = out + (size_t)b * (256 * 50);

    // ---- issue first efm K-step loads IMMEDIATELY (fills HBM pipe) ----
    const int r0 = rt * 128 + wv * 32;
    const float* ap0 = efm_b + (r0 + col16) * 256 + kg8;
    const float* ap1 = efm_b + (r0 + 16 + col16) * 256 + kg8;
    f32x4 lo0 = *(const f32x4*)ap0, hi0 = *(const f32x4*)(ap0 + 4);
    f32x4 lo1 = *(const f32x4*)ap1, hi1 = *(const f32x4*)(ap1 + 4);

    // ---- zero + stage W (bf16, swizzled) ----
    {
        unsigned* q = (unsigned*)w_s;            // 2048 dwords
        #pragma unroll
        for (int i = 0; i < 8; ++i) q[i * 256 + tid] = 0u;
    }
    __syncthreads();
    for (int i = tid; i < 625; i += 256) {       // 2500 f32
        f32x4 v = *(const f32x4*)(W + i * 4);
        int e = i * 4;
        #pragma unroll
        for (int j = 0; j < 4; ++j) {
            int o = (e + j) / 50, k = (e + j) % 50;
            w_s[swz(o, k)] = f2bf(v[j]);
        }
    }
    float bia[4];
    #pragma unroll
    for (int ot = 0; ot < 4; ++ot) {
        int c = ot * 16 + col16;
        bia[ot] = (c < 50) ? bias[c] : 0.f;
    }
    __syncthreads();

    // ---- phase 1: z = nfm @ W^T for ALL m; wave wv owns m in [wv*64,+64) ----
    {
        s16x8 wf[2][4];
        #pragma unroll
        for (int kk = 0; kk < 2; ++kk)
            #pragma unroll
            for (int ot = 0; ot < 4; ++ot) {
                int o = ot * 16 + col16;
                wf[kk][ot] = *(const s16x8*)&w_s[o * 64 + ((((kk << 2) | kg) ^ (o & 7)) << 3)];
            }
        #pragma unroll
        for (int mt = 0; mt < 4; ++mt) {
            int row = wv * 64 + mt * 16 + col16;
            const float* nr = nfm_b + row * 50;
            // a0: k = kg8 .. kg8+7 (all < 32, valid); 8-B aligned f32x2 loads
            float av[16];
            #pragma unroll
            for (int j = 0; j < 4; ++j) {
                f32x2 v = *(const f32x2*)(nr + kg8 + 2 * j);
                av[2 * j] = v.x; av[2 * j + 1] = v.y;
            }
            // a1: k = 32+kg8 .. 39+kg8; clamp addr in-bounds, mask k>=50 to 0
            #pragma unroll
            for (int j = 0; j < 4; ++j) {
                int k_e  = 32 + kg8 + 2 * j;
                int kcl  = (k_e < 48) ? k_e : 48;
                f32x2 v  = *(const f32x2*)(nr + kcl);
                av[8 + 2 * j]     = (k_e < 50)     ? v.x : 0.f;
                av[8 + 2 * j + 1] = (k_e + 1 < 50) ? v.y : 0.f;
            }
            s16x8 a0f, a1f;
            #pragma unroll
            for (int j = 0; j < 8; ++j) {
                a0f[j] = (short)f2bf(av[j]);
                a1f[j] = (short)f2bf(av[8 + j]);
            }
            #pragma unroll
            for (int ot = 0; ot < 4; ++ot) {
                f32x4 acc = {0.f, 0.f, 0.f, 0.f};
                acc = __builtin_amdgcn_mfma_f32_16x16x32_bf16(a0f, wf[0][ot], acc, 0, 0, 0);
                acc = __builtin_amdgcn_mfma_f32_16x16x32_bf16(a1f, wf[1][ot], acc, 0, 0, 0);
                // D layout: col = lane&15 (=o), row = kg*4 + r (=m offset)
                int m = wv * 64 + mt * 16 + kg * 4;
                int o = ot * 16 + col16;
                *(unsigned*)&z_s[o * ZSTR + m]     = bfpair(acc[0], acc[1]);
                *(unsigned*)&z_s[o * ZSTR + m + 2] = bfpair(acc[2], acc[3]);
            }
        }
    }
    __syncthreads();

    // ---- phase 2: out = relu(efm @ z + bias); wave owns 32 rows ----
    f32x4 acc[2][4];
    #pragma unroll
    for (int mt = 0; mt < 2; ++mt)
        #pragma unroll
        for (int ot = 0; ot < 4; ++ot)
            acc[mt][ot] = (f32x4){0.f, 0.f, 0.f, 0.f};

    #pragma unroll
    for (int ks = 0; ks < 8; ++ks) {
        f32x4 nlo0, nhi0, nlo1, nhi1;
        if (ks < 7) {                            // depth-1 reg prefetch
            const float* p0 = ap0 + (ks + 1) * 32;
            const float* p1 = ap1 + (ks + 1) * 32;
            nlo0 = *(const f32x4*)p0; nhi0 = *(const f32x4*)(p0 + 4);
            nlo1 = *(const f32x4*)p1; nhi1 = *(const f32x4*)(p1 + 4);
        }
        s16x8 bf[4];
        #pragma unroll
        for (int ot = 0; ot < 4; ++ot)
            bf[ot] = *(const s16x8*)&z_s[(ot * 16 + col16) * ZSTR + ks * 32 + kg8];

        s16x8 a0 = cvt8(lo0, hi0);
        s16x8 a1 = cvt8(lo1, hi1);
        #pragma unroll
        for (int ot = 0; ot < 4; ++ot) {
            acc[0][ot] = __builtin_amdgcn_mfma_f32_16x16x32_bf16(a0, bf[ot], acc[0][ot], 0, 0, 0);
            acc[1][ot] = __builtin_amdgcn_mfma_f32_16x16x32_bf16(a1, bf[ot], acc[1][ot], 0, 0, 0);
        }
        lo0 = nlo0; hi0 = nhi0; lo1 = nlo1; hi1 = nhi1;
    }

    // ---- epilogue: bias + relu + masked store (o < 50) ----
    #pragma unroll
    for (int mt = 0; mt < 2; ++mt)
        #pragma unroll
        for (int ot = 0; ot < 4; ++ot) {
            int o = ot * 16 + col16;
            if (o < 50) {
                #pragma unroll
                for (int r = 0; r < 4; ++r) {
                    int n = r0 + mt * 16 + kg * 4 + r;
                    out_b[n * 50 + o] = fmaxf(acc[mt][ot][r] + bia[ot], 0.f);
                }
            }
        }
}

extern "C" void kernel_launch(void* const* d_in, const int* in_sizes, int n_in,
                              void* d_out, int out_size, void* d_ws, size_t ws_size,
                              hipStream_t stream) {
    const float* nfm  = (const float*)d_in[0];   // [512,256,50]
    const float* efm  = (const float*)d_in[1];   // [512,256,256]
    const float* W    = (const float*)d_in[2];   // [50,50]
    const float* bias = (const float*)d_in[3];   // [50]
    float* out = (float*)d_out;                  // [512,256,50]

    // TIMING PROBE: 3 idempotent launches. dur = F + K_cold + 2*K_warm.
    // Next round single-launch: (dur_R4 - dur_R5)/2 = K_warm, isolating
    // the fixed harness-reset overhead F from kernel time K.
    gconv_v4<<<dim3(1024), dim3(256), 0, stream>>>(nfm, efm, W, bias, out);
    gconv_v4<<<dim3(1024), dim3(256), 0, stream>>>(nfm, efm, W, bias, out);
    gconv_v4<<<dim3(1024), dim3(256), 0, stream>>>(nfm, efm, W, bias, out);
}

// Round 7
// 234.704 us; speedup vs baseline: 1.2657x; 1.2657x over previous
//
#include <hip/hip_runtime.h>
#include <hip/hip_bf16.h>

// out[b,n,o] = relu( sum_m efm[b,n,m] * z[b,m,o] + bias[o] ),
// z[b,m,o]   = sum_d nfm[b,m,d] * W[o,d]        (matmul associativity)
//
// v5 split:
//  A: z (bf16, transposed [o][m], padded 64x264) -> d_ws   (~10 us)
//  B: pure streaming GEMM, 1024 blocks x 256 thr (exactly 4/CU, 16 waves/CU),
//     LDS = z only, depth-2 register prefetch, no barriers in main loop.

typedef float f32x4 __attribute__((ext_vector_type(4)));
typedef short s16x8 __attribute__((ext_vector_type(8)));

#define AS1C(p) ((const __attribute__((address_space(1))) unsigned int*)(p))
#define AS3(p)  ((__attribute__((address_space(3))) unsigned int*)(p))

#define ZSTR     264                      // padded m-stride (bf16 elems)
#define Z_ELEMS  (64 * ZSTR)              // 16896 elems = 33792 B per batch
#define Z_CHUNKS (Z_ELEMS * 2 / 16)       // 2112 16-byte chunks

__device__ __forceinline__ unsigned short f2bf(float f) {
    return __builtin_bit_cast(unsigned short, __float2bfloat16(f));
}
__device__ __forceinline__ s16x8 cvt8(f32x4 lo, f32x4 hi) {
    s16x8 r;
    #pragma unroll
    for (int j = 0; j < 4; ++j) {
        r[j]     = (short)f2bf(lo[j]);
        r[4 + j] = (short)f2bf(hi[j]);
    }
    return r;
}

// ---------------- Kernel A: z = bf16(nfm @ W^T), transposed, -> ws --------
__global__ __launch_bounds__(256, 4)
void compute_z(const float* __restrict__ nfm, const float* __restrict__ W,
               unsigned short* __restrict__ zws)
{
    __shared__ unsigned short nfm_s[256 * 72];
    __shared__ unsigned short w_s[64 * 72];
    __shared__ unsigned short z_s[Z_ELEMS];

    const int tid   = threadIdx.x;
    const int lane  = tid & 63;
    const int wv    = tid >> 6;          // 0..3
    const int col16 = lane & 15;
    const int kg    = lane >> 4;
    const int kg8   = kg * 8;
    const int b     = blockIdx.x;
    const float* nfm_b = nfm + (size_t)b * (256 * 50);

    {   // zero padded staging buffers
        unsigned* p = (unsigned*)nfm_s;
        for (int i = tid; i < 256 * 72 / 2; i += 256) p[i] = 0u;
        unsigned* q = (unsigned*)w_s;
        for (int i = tid; i < 64 * 72 / 2; i += 256) q[i] = 0u;
    }
    __syncthreads();

    for (int i = tid; i < 3200; i += 256) {          // 12800 f32
        f32x4 v = *(const f32x4*)(nfm_b + i * 4);
        int e = i * 4;
        #pragma unroll
        for (int j = 0; j < 4; ++j) {
            int r = (e + j) / 50, k = (e + j) % 50;
            nfm_s[r * 72 + k] = f2bf(v[j]);
        }
    }
    for (int i = tid; i < 625; i += 256) {           // 2500 f32
        f32x4 v = *(const f32x4*)(W + i * 4);
        int e = i * 4;
        #pragma unroll
        for (int j = 0; j < 4; ++j) {
            int o = (e + j) / 50, k = (e + j) % 50;
            w_s[o * 72 + k] = f2bf(v[j]);
        }
    }
    __syncthreads();

    s16x8 wf[2][4];
    #pragma unroll
    for (int kk = 0; kk < 2; ++kk)
        #pragma unroll
        for (int ot = 0; ot < 4; ++ot)
            wf[kk][ot] = *(const s16x8*)&w_s[(ot * 16 + col16) * 72 + kk * 32 + kg8];

    #pragma unroll
    for (int mt = 0; mt < 4; ++mt) {                 // wave owns 64 m-rows
        int row = wv * 64 + mt * 16 + col16;
        s16x8 a0 = *(const s16x8*)&nfm_s[row * 72 + kg8];
        s16x8 a1 = *(const s16x8*)&nfm_s[row * 72 + 32 + kg8];
        #pragma unroll
        for (int ot = 0; ot < 4; ++ot) {
            f32x4 acc = {0.f, 0.f, 0.f, 0.f};
            acc = __builtin_amdgcn_mfma_f32_16x16x32_bf16(a0, wf[0][ot], acc, 0, 0, 0);
            acc = __builtin_amdgcn_mfma_f32_16x16x32_bf16(a1, wf[1][ot], acc, 0, 0, 0);
            #pragma unroll
            for (int r = 0; r < 4; ++r) {
                int m = wv * 64 + mt * 16 + kg * 4 + r;
                int o = ot * 16 + col16;
                z_s[o * ZSTR + m] = f2bf(acc[r]);    // transposed
            }
        }
    }
    __syncthreads();

    uint4* dst = (uint4*)(zws + (size_t)b * Z_ELEMS);
    const uint4* src = (const uint4*)z_s;
    for (int i = tid; i < Z_CHUNKS; i += 256) dst[i] = src[i];
}

// ---------------- Kernel B: out = relu(efm @ z + bias) --------------------
__global__ __launch_bounds__(256, 4)
void gemm_out_v5(const float* __restrict__ efm,
                 const unsigned short* __restrict__ zws,
                 const float* __restrict__ bias,
                 float* __restrict__ out)
{
    __shared__ unsigned short z_s[Z_ELEMS];          // 33792 B -> 4 blocks/CU

    const int tid   = threadIdx.x;
    const int lane  = tid & 63;
    const int wv    = tid >> 6;
    const int col16 = lane & 15;
    const int kg    = lane >> 4;
    const int kg8   = kg * 8;
    const int bid   = blockIdx.x;
    const int b     = bid >> 1;
    const int rt    = bid & 1;

    // 1) async stage z[b] -> LDS (linear dest; pad pre-baked in ws)
    const unsigned short* zb = zws + (size_t)b * Z_ELEMS;
    #pragma unroll
    for (int i = 0; i < 9; ++i) {
        int idx = i * 256 + tid;                     // 16B chunk id
        if (idx < Z_CHUNKS) {                        // wave-uniform guard
            __builtin_amdgcn_global_load_lds(
                AS1C((const char*)zb + (size_t)idx * 16),
                AS3((char*)z_s + (i * 256 + wv * 64) * 16), 16, 0, 0);
        }
    }

    const float* efm_b = efm + (size_t)b * (256 * 256);
    float*       out_b = out + (size_t)b * (256 * 50);
    const int r0 = rt * 128 + wv * 32;               // wave's 32 rows
    const float* ap0 = efm_b + (r0 + col16) * 256 + kg8;
    const float* ap1 = ap0 + 16 * 256;

    // 2) A-operand preloads for ks=0,1 issued BEFORE the barrier:
    //    their HBM latency hides under the z staging drain.
    f32x4 A[2][4];                                   // [slot][lo0,hi0,lo1,hi1]
    #define LOADA(slot, step) {                                        \
        const float* _p0 = ap0 + (step) * 32;                          \
        const float* _p1 = ap1 + (step) * 32;                          \
        A[slot][0] = *(const f32x4*)_p0;  A[slot][1] = *(const f32x4*)(_p0 + 4); \
        A[slot][2] = *(const f32x4*)_p1;  A[slot][3] = *(const f32x4*)(_p1 + 4); }
    LOADA(0, 0)
    LOADA(1, 1)

    float bia[4];
    #pragma unroll
    for (int ot = 0; ot < 4; ++ot) {
        int c = ot * 16 + col16;
        bia[ot] = (c < 50) ? bias[c] : 0.f;
    }
    __syncthreads();                                 // drains vmcnt + lgkm

    f32x4 acc[2][4];
    #pragma unroll
    for (int mt = 0; mt < 2; ++mt)
        #pragma unroll
        for (int ot = 0; ot < 4; ++ot)
            acc[mt][ot] = (f32x4){0.f, 0.f, 0.f, 0.f};

    // 3) main loop: fully unrolled, depth-2 rolling prefetch (slot = ks&1,
    //    compile-time under unroll -> stays in registers, rule-#20-safe).
    #pragma unroll
    for (int ks = 0; ks < 8; ++ks) {
        const int cur = ks & 1;
        s16x8 a0 = cvt8(A[cur][0], A[cur][1]);
        s16x8 a1 = cvt8(A[cur][2], A[cur][3]);
        if (ks < 6) LOADA(cur, ks + 2)               // refill freed slot

        s16x8 bf[4];
        #pragma unroll
        for (int ot = 0; ot < 4; ++ot)
            bf[ot] = *(const s16x8*)&z_s[(ot * 16 + col16) * ZSTR + ks * 32 + kg8];

        #pragma unroll
        for (int ot = 0; ot < 4; ++ot) {
            acc[0][ot] = __builtin_amdgcn_mfma_f32_16x16x32_bf16(a0, bf[ot], acc[0][ot], 0, 0, 0);
            acc[1][ot] = __builtin_amdgcn_mfma_f32_16x16x32_bf16(a1, bf[ot], acc[1][ot], 0, 0, 0);
        }
    }
    #undef LOADA

    // 4) epilogue: bias + relu + masked store (o < 50)
    #pragma unroll
    for (int mt = 0; mt < 2; ++mt)
        #pragma unroll
        for (int ot = 0; ot < 4; ++ot) {
            int o = ot * 16 + col16;
            if (o < 50) {
                #pragma unroll
                for (int r = 0; r < 4; ++r) {
                    int n = r0 + mt * 16 + kg * 4 + r;
                    out_b[n * 50 + o] = fmaxf(acc[mt][ot][r] + bia[ot], 0.f);
                }
            }
        }
}

// ---------------- fallback (ws too small): v4 monolithic ------------------
__global__ __launch_bounds__(256, 3)
void gconv_v4(const float* __restrict__ nfm, const float* __restrict__ efm,
              const float* __restrict__ W, const float* __restrict__ bias,
              float* __restrict__ out)
{
    __shared__ unsigned short w_s[64 * 64];
    __shared__ unsigned short z_s[64 * ZSTR];

    const int tid = threadIdx.x, lane = tid & 63, wv = tid >> 6;
    const int col16 = lane & 15, kg = lane >> 4, kg8 = kg * 8;
    const int bid = blockIdx.x, b = bid >> 1, rt = bid & 1;
    const float* nfm_b = nfm + (size_t)b * (256 * 50);
    const float* efm_b = efm + (size_t)b * (256 * 256);
    float*       out_b = out + (size_t)b * (256 * 50);

    const int r0 = rt * 128 + wv * 32;
    const float* ap0 = efm_b + (r0 + col16) * 256 + kg8;
    const float* ap1 = ap0 + 16 * 256;
    f32x4 lo0 = *(const f32x4*)ap0, hi0 = *(const f32x4*)(ap0 + 4);
    f32x4 lo1 = *(const f32x4*)ap1, hi1 = *(const f32x4*)(ap1 + 4);

    {
        unsigned* q = (unsigned*)w_s;
        #pragma unroll
        for (int i = 0; i < 8; ++i) q[i * 256 + tid] = 0u;
    }
    __syncthreads();
    for (int i = tid; i < 625; i += 256) {
        f32x4 v = *(const f32x4*)(W + i * 4);
        int e = i * 4;
        #pragma unroll
        for (int j = 0; j < 4; ++j) {
            int o = (e + j) / 50, k = (e + j) % 50;
            w_s[o * 64 + ((((k >> 3) ^ (o & 7)) << 3) | (k & 7))] = f2bf(v[j]);
        }
    }
    float bia[4];
    #pragma unroll
    for (int ot = 0; ot < 4; ++ot) {
        int c = ot * 16 + col16;
        bia[ot] = (c < 50) ? bias[c] : 0.f;
    }
    __syncthreads();
    {
        s16x8 wf[2][4];
        #pragma unroll
        for (int kk = 0; kk < 2; ++kk)
            #pragma unroll
            for (int ot = 0; ot < 4; ++ot) {
                int o = ot * 16 + col16;
                wf[kk][ot] = *(const s16x8*)&w_s[o * 64 + ((((kk << 2) | kg) ^ (o & 7)) << 3)];
            }
        #pragma unroll
        for (int mt = 0; mt < 4; ++mt) {
            int row = wv * 64 + mt * 16 + col16;
            const float* nr = nfm_b + row * 50;
            float av[16];
            #pragma unroll
            for (int j = 0; j < 4; ++j) {
                float2 v = *(const float2*)(nr + kg8 + 2 * j);
                av[2 * j] = v.x; av[2 * j + 1] = v.y;
            }
            #pragma unroll
            for (int j = 0; j < 4; ++j) {
                int k_e = 32 + kg8 + 2 * j;
                int kcl = (k_e < 48) ? k_e : 48;
                float2 v = *(const float2*)(nr + kcl);
                av[8 + 2 * j]     = (k_e < 50)     ? v.x : 0.f;
                av[8 + 2 * j + 1] = (k_e + 1 < 50) ? v.y : 0.f;
            }
            s16x8 a0f, a1f;
            #pragma unroll
            for (int j = 0; j < 8; ++j) {
                a0f[j] = (short)f2bf(av[j]);
                a1f[j] = (short)f2bf(av[8 + j]);
            }
            #pragma unroll
            for (int ot = 0; ot < 4; ++ot) {
                f32x4 acc = {0.f, 0.f, 0.f, 0.f};
                acc = __builtin_amdgcn_mfma_f32_16x16x32_bf16(a0f, wf[0][ot], acc, 0, 0, 0);
                acc = __builtin_amdgcn_mfma_f32_16x16x32_bf16(a1f, wf[1][ot], acc, 0, 0, 0);
                int m = wv * 64 + mt * 16 + kg * 4;
                int o = ot * 16 + col16;
                unsigned p0 = (unsigned)f2bf(acc[0]) | ((unsigned)f2bf(acc[1]) << 16);
                unsigned p1 = (unsigned)f2bf(acc[2]) | ((unsigned)f2bf(acc[3]) << 16);
                *(unsigned*)&z_s[o * ZSTR + m]     = p0;
                *(unsigned*)&z_s[o * ZSTR + m + 2] = p1;
            }
        }
    }
    __syncthreads();
    f32x4 acc[2][4];
    #pragma unroll
    for (int mt = 0; mt < 2; ++mt)
        #pragma unroll
        for (int ot = 0; ot < 4; ++ot)
            acc[mt][ot] = (f32x4){0.f, 0.f, 0.f, 0.f};
    #pragma unroll
    for (int ks = 0; ks < 8; ++ks) {
        f32x4 nlo0, nhi0, nlo1, nhi1;
        if (ks < 7) {
            const float* p0 = ap0 + (ks + 1) * 32;
            const float* p1 = ap1 + (ks + 1) * 32;
            nlo0 = *(const f32x4*)p0; nhi0 = *(const f32x4*)(p0 + 4);
            nlo1 = *(const f32x4*)p1; nhi1 = *(const f32x4*)(p1 + 4);
        }
        s16x8 bf[4];
        #pragma unroll
        for (int ot = 0; ot < 4; ++ot)
            bf[ot] = *(const s16x8*)&z_s[(ot * 16 + col16) * ZSTR + ks * 32 + kg8];
        s16x8 a0 = cvt8(lo0, hi0);
        s16x8 a1 = cvt8(lo1, hi1);
        #pragma unroll
        for (int ot = 0; ot < 4; ++ot) {
            acc[0][ot] = __builtin_amdgcn_mfma_f32_16x16x32_bf16(a0, bf[ot], acc[0][ot], 0, 0, 0);
            acc[1][ot] = __builtin_amdgcn_mfma_f32_16x16x32_bf16(a1, bf[ot], acc[1][ot], 0, 0, 0);
        }
        lo0 = nlo0; hi0 = nhi0; lo1 = nlo1; hi1 = nhi1;
    }
    #pragma unroll
    for (int mt = 0; mt < 2; ++mt)
        #pragma unroll
        for (int ot = 0; ot < 4; ++ot) {
            int o = ot * 16 + col16;
            if (o < 50) {
                #pragma unroll
                for (int r = 0; r < 4; ++r) {
                    int n = r0 + mt * 16 + kg * 4 + r;
                    out_b[n * 50 + o] = fmaxf(acc[mt][ot][r] + bia[ot], 0.f);
                }
            }
        }
}

extern "C" void kernel_launch(void* const* d_in, const int* in_sizes, int n_in,
                              void* d_out, int out_size, void* d_ws, size_t ws_size,
                              hipStream_t stream) {
    const float* nfm  = (const float*)d_in[0];   // [512,256,50]
    const float* efm  = (const float*)d_in[1];   // [512,256,256]
    const float* W    = (const float*)d_in[2];   // [50,50]
    const float* bias = (const float*)d_in[3];   // [50]
    float* out = (float*)d_out;                  // [512,256,50]

    const size_t need = (size_t)512 * Z_ELEMS * sizeof(unsigned short);  // ~17.3 MB
    if (ws_size >= need) {
        unsigned short* zws = (unsigned short*)d_ws;
        compute_z<<<dim3(512), dim3(256), 0, stream>>>(nfm, W, zws);
        gemm_out_v5<<<dim3(1024), dim3(256), 0, stream>>>(efm, zws, bias, out);
    } else {
        gconv_v4<<<dim3(1024), dim3(256), 0, stream>>>(nfm, efm, W, bias, out);
    }
}